// Round 3
// baseline (744.066 us; speedup 1.0000x reference)
//
#include <hip/hip_runtime.h>
#include <stdint.h>

#define S_LEN 2048
#define DMODEL 4096
#define NHEAD 32
#define HDIM 128

typedef __attribute__((ext_vector_type(8))) short bf16x8;
typedef __attribute__((ext_vector_type(4))) float f32x4;

__device__ __forceinline__ unsigned short f2bf(float f) {
    union { float f; unsigned u; } v; v.f = f;
    unsigned u = v.u;
    unsigned r = (u + 0x7FFFu + ((u >> 16) & 1u)) >> 16;   // RNE
    return (unsigned short)r;
}
__device__ __forceinline__ float bf2f(unsigned short h) {
    union { unsigned u; float f; } v; v.u = ((unsigned)h) << 16;
    return v.f;
}

// ---------- elementwise f32 -> bf16 (4 per thread) ----------
__global__ void convert_x_kernel(const float* __restrict__ x,
                                 unsigned short* __restrict__ xb, int n4) {
    int t = blockIdx.x * blockDim.x + threadIdx.x;
    if (t >= n4) return;
    float4 v = ((const float4*)x)[t];
    ushort4 o;
    o.x = f2bf(v.x); o.y = f2bf(v.y); o.z = f2bf(v.z); o.w = f2bf(v.w);
    ((ushort4*)xb)[t] = o;
}

// ---------- transpose+convert weight: w[k][n] f32 -> wt[n][k] bf16 ----------
__global__ void convert_wt_kernel(const float* __restrict__ w,
                                  unsigned short* __restrict__ wt) {
    __shared__ unsigned short t[64][65];
    int n0 = blockIdx.x * 64, k0 = blockIdx.y * 64;
    for (int i = 0; i < 16; ++i) {
        int o = threadIdx.x + i * 256;
        int r = o >> 6, c = o & 63;
        t[r][c] = f2bf(w[(size_t)(k0 + r) * DMODEL + n0 + c]);
    }
    __syncthreads();
    for (int i = 0; i < 16; ++i) {
        int o = threadIdx.x + i * 256;
        int rr = o >> 6, kk = o & 63;
        wt[(size_t)(n0 + rr) * DMODEL + k0 + kk] = t[kk][rr];
    }
}

// ============================================================================
// GEMM: 8-phase counted-vmcnt schedule (verified; unchanged this round)
// ============================================================================

#define MFMA16(a, b, c) __builtin_amdgcn_mfma_f32_16x16x32_bf16(a, b, c, 0, 0, 0)

#define GLDS(g, l) __builtin_amdgcn_global_load_lds( \
    (__attribute__((address_space(1))) unsigned int*)(g), \
    (__attribute__((address_space(3))) unsigned int*)(l), 16, 0, 0)

#define VMCNT_(n) asm volatile("s_waitcnt vmcnt(" #n ")" ::: "memory")
#define VMCNT(n) VMCNT_(n)

#define PH_SYNC() \
    __builtin_amdgcn_sched_barrier(0); \
    __builtin_amdgcn_s_barrier(); \
    asm volatile("s_waitcnt lgkmcnt(0)" ::: "memory"); \
    __builtin_amdgcn_sched_barrier(0)

#define PH_END() \
    __builtin_amdgcn_s_setprio(0); \
    __builtin_amdgcn_sched_barrier(0); \
    __builtin_amdgcn_s_barrier(); \
    __builtin_amdgcn_sched_barrier(0)

#define PH_END_VM(VM) \
    __builtin_amdgcn_s_setprio(0); \
    __builtin_amdgcn_sched_barrier(0); \
    VMCNT(VM); \
    __builtin_amdgcn_s_barrier(); \
    __builtin_amdgcn_sched_barrier(0)

#define STAGE_A(T, PAR, J) do { \
    size_t ko_ = (size_t)(T) * 64 + (J) * 32; \
    GLDS(gA0 + ko_, As + ((PAR) * 2 + (J)) * 8192 + w * 512); \
    GLDS(gA1 + ko_, As + ((PAR) * 2 + (J)) * 8192 + 4096 + w * 512); \
} while (0)
#define STAGE_B(T, PAR, J) do { \
    size_t ko_ = (size_t)(T) * 64 + (J) * 32; \
    GLDS(gB + ko_, Bs + ((PAR) * 2 + (J)) * 4096 + w * 512); \
} while (0)

#define TILE(T, P, S1, S2, VM2, VM4) do { \
    const unsigned short* AsT = As + (P) * 16384; \
    const unsigned short* BsT = Bs + (P) * 8192; \
    bf16x8 af0, af1, af2, af3, bf0, bf1, bf2, bf3; \
    af0 = *(const bf16x8*)&AsT[offA0]; \
    af1 = *(const bf16x8*)&AsT[offA1]; \
    af2 = *(const bf16x8*)&AsT[offA2]; \
    af3 = *(const bf16x8*)&AsT[offA3]; \
    bf0 = *(const bf16x8*)&BsT[offB0]; \
    bf1 = *(const bf16x8*)&BsT[offB1]; \
    if (S1) STAGE_A((T) + 1, (P) ^ 1, 1); \
    PH_SYNC(); \
    __builtin_amdgcn_s_setprio(1); \
    acc[0][0] = MFMA16(af0, bf0, acc[0][0]); \
    acc[1][0] = MFMA16(af1, bf0, acc[1][0]); \
    acc[2][0] = MFMA16(af2, bf0, acc[2][0]); \
    acc[3][0] = MFMA16(af3, bf0, acc[3][0]); \
    acc[0][1] = MFMA16(af0, bf1, acc[0][1]); \
    acc[1][1] = MFMA16(af1, bf1, acc[1][1]); \
    acc[2][1] = MFMA16(af2, bf1, acc[2][1]); \
    acc[3][1] = MFMA16(af3, bf1, acc[3][1]); \
    PH_END(); \
    bf2 = *(const bf16x8*)&BsT[offB2]; \
    bf3 = *(const bf16x8*)&BsT[offB3]; \
    if (S1) STAGE_B((T) + 1, (P) ^ 1, 1); \
    PH_SYNC(); \
    __builtin_amdgcn_s_setprio(1); \
    acc[0][2] = MFMA16(af0, bf2, acc[0][2]); \
    acc[1][2] = MFMA16(af1, bf2, acc[1][2]); \
    acc[2][2] = MFMA16(af2, bf2, acc[2][2]); \
    acc[3][2] = MFMA16(af3, bf2, acc[3][2]); \
    acc[0][3] = MFMA16(af0, bf3, acc[0][3]); \
    acc[1][3] = MFMA16(af1, bf3, acc[1][3]); \
    acc[2][3] = MFMA16(af2, bf3, acc[2][3]); \
    acc[3][3] = MFMA16(af3, bf3, acc[3][3]); \
    PH_END_VM(VM2); \
    af0 = *(const bf16x8*)&AsT[8192 + offA0]; \
    af1 = *(const bf16x8*)&AsT[8192 + offA1]; \
    af2 = *(const bf16x8*)&AsT[8192 + offA2]; \
    af3 = *(const bf16x8*)&AsT[8192 + offA3]; \
    bf0 = *(const bf16x8*)&BsT[4096 + offB0]; \
    bf1 = *(const bf16x8*)&BsT[4096 + offB1]; \
    if (S2) STAGE_A((T) + 2, (P), 0); \
    PH_SYNC(); \
    __builtin_amdgcn_s_setprio(1); \
    acc[0][0] = MFMA16(af0, bf0, acc[0][0]); \
    acc[1][0] = MFMA16(af1, bf0, acc[1][0]); \
    acc[2][0] = MFMA16(af2, bf0, acc[2][0]); \
    acc[3][0] = MFMA16(af3, bf0, acc[3][0]); \
    acc[0][1] = MFMA16(af0, bf1, acc[0][1]); \
    acc[1][1] = MFMA16(af1, bf1, acc[1][1]); \
    acc[2][1] = MFMA16(af2, bf1, acc[2][1]); \
    acc[3][1] = MFMA16(af3, bf1, acc[3][1]); \
    PH_END(); \
    bf2 = *(const bf16x8*)&BsT[4096 + offB2]; \
    bf3 = *(const bf16x8*)&BsT[4096 + offB3]; \
    if (S2) STAGE_B((T) + 2, (P), 0); \
    PH_SYNC(); \
    __builtin_amdgcn_s_setprio(1); \
    acc[0][2] = MFMA16(af0, bf2, acc[0][2]); \
    acc[1][2] = MFMA16(af1, bf2, acc[1][2]); \
    acc[2][2] = MFMA16(af2, bf2, acc[2][2]); \
    acc[3][2] = MFMA16(af3, bf2, acc[3][2]); \
    acc[0][3] = MFMA16(af0, bf3, acc[0][3]); \
    acc[1][3] = MFMA16(af1, bf3, acc[1][3]); \
    acc[2][3] = MFMA16(af2, bf3, acc[2][3]); \
    acc[3][3] = MFMA16(af3, bf3, acc[3][3]); \
    PH_END_VM(VM4); \
} while (0)

template<int STORE_MODE>
__global__ __launch_bounds__(512, 2)
void gemm8p_kernel(const unsigned short* __restrict__ A,
                   const unsigned short* __restrict__ BT,
                   void* __restrict__ C) {
    constexpr int M = S_LEN, N = DMODEL, K = DMODEL;
    constexpr int NT = K / 64;
    extern __shared__ __align__(16) unsigned short sm[];
    unsigned short* As = sm;
    unsigned short* Bs = sm + 32768;

    const int tid = threadIdx.x;
    const int lane = tid & 63;
    const int w = tid >> 6;
    const int wr = w >> 1, wc = w & 1;
    const int q = lane >> 4, lm = lane & 15;

    int orig = blockIdx.y * gridDim.x + blockIdx.x;
    const int by = orig & 7;
    const int bx = orig >> 3;
    const int m0 = by * 256, n0 = bx * 128;

    const int c4 = tid & 3, r4 = tid >> 2, s4 = (tid >> 3) & 3;
    const unsigned short* gA0 = A + (size_t)(m0 + r4) * K + ((c4 ^ s4) * 8);
    const unsigned short* gA1 = gA0 + (size_t)128 * K;
    const unsigned short* gB  = BT + (size_t)(n0 + r4) * K + ((c4 ^ s4) * 8);

#define FRAGOFF(r_) ((r_) * 32 + ((q ^ (((r_) >> 1) & 3)) * 8))
    const int rA = wr * 64 + lm, rB = wc * 64 + lm;
    const int offA0 = FRAGOFF(rA);
    const int offA1 = FRAGOFF(rA + 16);
    const int offA2 = FRAGOFF(rA + 32);
    const int offA3 = FRAGOFF(rA + 48);
    const int offB0 = FRAGOFF(rB);
    const int offB1 = FRAGOFF(rB + 16);
    const int offB2 = FRAGOFF(rB + 32);
    const int offB3 = FRAGOFF(rB + 48);
#undef FRAGOFF

    f32x4 zero = {0.f, 0.f, 0.f, 0.f};
    f32x4 acc[4][4];
    for (int i = 0; i < 4; ++i)
        for (int j = 0; j < 4; ++j) acc[i][j] = zero;

    STAGE_A(0, 0, 0); STAGE_B(0, 0, 0);
    STAGE_A(0, 0, 1); STAGE_B(0, 0, 1);
    STAGE_A(1, 1, 0); STAGE_B(1, 1, 0);
    VMCNT(6);
    __builtin_amdgcn_s_barrier();
    __builtin_amdgcn_sched_barrier(0);

    for (int t = 0; t < NT - 2; t += 2) {
        TILE(t, 0, true, true, 6, 6);
        TILE(t + 1, 1, true, true, 6, 6);
    }
    TILE(NT - 2, 0, true, false, 6, 3);
    TILE(NT - 1, 1, false, false, 0, 0);

    for (int mi = 0; mi < 4; ++mi) {
        int mbase = m0 + wr * 64 + mi * 16 + q * 4;
        for (int ni = 0; ni < 4; ++ni) {
            int n = n0 + wc * 64 + ni * 16 + lm;
            if (STORE_MODE == 0) {
                unsigned short* Cb = (unsigned short*)C;
                for (int r = 0; r < 4; ++r)
                    Cb[(size_t)(mbase + r) * N + n] = f2bf(acc[mi][ni][r]);
            } else if (STORE_MODE == 1) {
                unsigned short* Cb = (unsigned short*)C;
                ushort4 v;
                v.x = f2bf(acc[mi][ni][0]); v.y = f2bf(acc[mi][ni][1]);
                v.z = f2bf(acc[mi][ni][2]); v.w = f2bf(acc[mi][ni][3]);
                *(ushort4*)&Cb[(size_t)n * M + mbase] = v;
            } else {
                float* Cf = (float*)C;
                for (int r = 0; r < 4; ++r)
                    Cf[(size_t)(mbase + r) * N + n] = acc[mi][ni][r];
            }
        }
    }
}

// ---------- RoPE in-place on q (fused 1/sqrt(hd)) and k ----------
__global__ void rope_kernel(unsigned short* __restrict__ qb,
                            unsigned short* __restrict__ kb) {
    int t = blockIdx.x * blockDim.x + threadIdx.x;
    if (t >= S_LEN * DMODEL / 2) return;
    int s = t >> 11;
    int p = t & 2047;
    int j = p & 63;
    float ang = (float)s * exp2f((float)j * -0.2076205059304602f);
    float sn, cs;
    sincosf(ang, &sn, &cs);
    size_t idx = (size_t)s * DMODEL + 2 * p;
    const float SC = 0.08838834764831845f;
    float a0 = bf2f(qb[idx]), a1 = bf2f(qb[idx + 1]);
    qb[idx]     = f2bf((a0 * cs - a1 * sn) * SC);
    qb[idx + 1] = f2bf((a0 * sn + a1 * cs) * SC);
    float b0 = bf2f(kb[idx]), b1 = bf2f(kb[idx + 1]);
    kb[idx]     = f2bf(b0 * cs - b1 * sn);
    kb[idx + 1] = f2bf(b0 * sn + b1 * cs);
}

// ============================================================================
// flash attention v4: swapped QK^T (S^T via mfma(K,Q)) -> in-lane softmax with
// 2-step shuffle reductions; P redistributed to PV A-operand in-register
// (cvt_pk + 16 shfl + 8 sel per q-tile) -- no P LDS roundtrip.
// K staged via global_load_lds into double-buffered LDS (32KB), ONE barrier
// per chunk, vmcnt(0) drained only at end-of-chunk (issue-early -> hidden).
// V read directly from global (vt is [d][S]; L2-resident per head), issued at
// chunk top, consumed in PV ~2000cyc later.
// Block: 4 waves x 32q = 128 q; grid (16,32) = 512 blocks.
// ============================================================================
__global__ __launch_bounds__(256, 2)
void attn_kernel(const unsigned short* __restrict__ qb,
                 const unsigned short* __restrict__ kb,
                 const unsigned short* __restrict__ vt,
                 unsigned short* __restrict__ ab) {
    __shared__ __align__(16) unsigned short Ks[2][64 * 128];  // [buf][key][d], col swz c^=row&15
    const int t = threadIdx.x;
    const int lane = t & 63;
    const int w = t >> 6;
    const int h = blockIdx.y;
    const int q0 = ((int)gridDim.x - 1 - (int)blockIdx.x) * 128;  // longest first
    const int qw = q0 + w * 32;
    const int q = lane >> 4, lm = lane & 15;
    const int w16 = w * 16;

    // K staging: wave w, load j covers rows w16+j*4..+3; lane l -> row w16+j*4+(l>>4),
    // LDS col (l&15) [linear dest], global col (l&15)^(row&15) [inverse swizzle source]
#define ATT_STAGE(CHUNK, BUF) do { \
    size_t rbase_ = (size_t)((CHUNK) * 64); \
    _Pragma("unroll") \
    for (int j_ = 0; j_ < 4; ++j_) { \
        int rloc_ = w16 + j_ * 4 + (lane >> 4); \
        const unsigned short* src_ = kb + (rbase_ + rloc_) * DMODEL + h * HDIM \
                                     + (((lane & 15) ^ (rloc_ & 15)) * 8); \
        GLDS(src_, &Ks[BUF][(w16 + j_ * 4) * 128]); \
    } \
} while (0)

    // Q fragments (32 queries/wave = 2 q-tiles of 16)
    bf16x8 qf[2][4];
#pragma unroll
    for (int qt = 0; qt < 2; ++qt)
#pragma unroll
        for (int kc = 0; kc < 4; ++kc)
            qf[qt][kc] = *(const bf16x8*)&qb[(size_t)(qw + qt * 16 + lm) * DMODEL
                                            + h * HDIM + kc * 32 + q * 8];

    f32x4 zero = {0.f, 0.f, 0.f, 0.f};
    f32x4 o[2][8];
#pragma unroll
    for (int qt = 0; qt < 2; ++qt)
        for (int i = 0; i < 8; ++i) o[qt][i] = zero;
    float mrow[2] = {-1e30f, -1e30f};   // running max for query lm (per q-tile)
    float lrow[2] = {0.f, 0.f};

    const int nch = q0 / 64 + 2;

    // prologue: stage chunk 0
    ATT_STAGE(0, 0);
    VMCNT(0);
    __builtin_amdgcn_s_barrier();
    __builtin_amdgcn_sched_barrier(0);

    for (int c = 0; c < nch; ++c) {
        const int j0 = c * 64;
        const int p = c & 1;
        // issue next-chunk K staging first (drained at end-of-chunk barrier)
        if (c + 1 < nch) ATT_STAGE(c + 1, p ^ 1);

        if (j0 <= qw + 31) {    // wave-uniform causal skip
            // V direct from global (current chunk), issued early
            bf16x8 vf0[8], vf1[8];
#pragma unroll
            for (int nt = 0; nt < 8; ++nt) {
                const unsigned short* gv = vt + (size_t)(h * HDIM + nt * 16 + lm) * S_LEN
                                           + j0 + q * 8;
                vf0[nt] = *(const bf16x8*)gv;
                vf1[nt] = *(const bf16x8*)(gv + 32);
            }

            // ---- swapped QK^T: s[qt][ks][r] = S[query qw+qt*16+lm][key j0+ks*16+q*4+r]
            f32x4 s[2][4];
#pragma unroll
            for (int qt = 0; qt < 2; ++qt)
                for (int ks = 0; ks < 4; ++ks) s[qt][ks] = zero;
#pragma unroll
            for (int kc = 0; kc < 4; ++kc)
#pragma unroll
                for (int ks = 0; ks < 4; ++ks) {
                    bf16x8 kf = *(const bf16x8*)&Ks[p][(ks * 16 + lm) * 128
                                                      + (((kc * 4 + q) ^ lm) * 8)];
                    s[0][ks] = __builtin_amdgcn_mfma_f32_16x16x32_bf16(kf, qf[0][kc], s[0][ks], 0, 0, 0);
                    s[1][ks] = __builtin_amdgcn_mfma_f32_16x16x32_bf16(kf, qf[1][kc], s[1][ks], 0, 0, 0);
                }
            // causal mask: key > query -> -inf
            if (j0 + 63 > qw) {
#pragma unroll
                for (int qt = 0; qt < 2; ++qt)
#pragma unroll
                    for (int ks = 0; ks < 4; ++ks)
#pragma unroll
                        for (int r = 0; r < 4; ++r)
                            if (j0 + ks * 16 + q * 4 + r > qw + qt * 16 + lm)
                                s[qt][ks][r] = -1e30f;
            }

            // ---- in-lane softmax (16 vals per lane per qt) + 2 shuffle steps
            float alnv[2];
#pragma unroll
            for (int qt = 0; qt < 2; ++qt) {
                float m01 = fmaxf(fmaxf(s[qt][0][0], s[qt][0][1]), fmaxf(s[qt][0][2], s[qt][0][3]));
                float m11 = fmaxf(fmaxf(s[qt][1][0], s[qt][1][1]), fmaxf(s[qt][1][2], s[qt][1][3]));
                float m21 = fmaxf(fmaxf(s[qt][2][0], s[qt][2][1]), fmaxf(s[qt][2][2], s[qt][2][3]));
                float m31 = fmaxf(fmaxf(s[qt][3][0], s[qt][3][1]), fmaxf(s[qt][3][2], s[qt][3][3]));
                float mloc = fmaxf(fmaxf(m01, m11), fmaxf(m21, m31));
                mloc = fmaxf(mloc, __shfl_xor(mloc, 16));
                mloc = fmaxf(mloc, __shfl_xor(mloc, 32));
                float mn = fmaxf(mrow[qt], mloc);
                alnv[qt] = __expf(mrow[qt] - mn);
                mrow[qt] = mn;
#pragma unroll
                for (int ks = 0; ks < 4; ++ks)
#pragma unroll
                    for (int r = 0; r < 4; ++r)
                        s[qt][ks][r] = __expf(s[qt][ks][r] - mn);
                float r0 = (s[qt][0][0] + s[qt][0][1]) + (s[qt][0][2] + s[qt][0][3]);
                float r1 = (s[qt][1][0] + s[qt][1][1]) + (s[qt][1][2] + s[qt][1][3]);
                float r2 = (s[qt][2][0] + s[qt][2][1]) + (s[qt][2][2] + s[qt][2][3]);
                float r3 = (s[qt][3][0] + s[qt][3][1]) + (s[qt][3][2] + s[qt][3][3]);
                float rloc = (r0 + r1) + (r2 + r3);
                rloc += __shfl_xor(rloc, 16);
                rloc += __shfl_xor(rloc, 32);
                lrow[qt] = lrow[qt] * alnv[qt] + rloc;
            }

            // ---- pack P to bf16 pairs: Wd[qt][ks][u] = pk(p[2u], p[2u+1])
            unsigned Wd[2][4][2];
#pragma unroll
            for (int qt = 0; qt < 2; ++qt)
#pragma unroll
                for (int ks = 0; ks < 4; ++ks)
#pragma unroll
                    for (int u = 0; u < 2; ++u) {
                        unsigned wv;
                        asm("v_cvt_pk_bf16_f32 %0, %1, %2"
                            : "=v"(wv) : "v"(s[qt][ks][2 * u]), "v"(s[qt][ks][2 * u + 1]));
                        Wd[qt][ks][u] = wv;
                    }

            // ---- redistribute P to PV A-operand layout (row=query=lm, k=key)
            // target lane (q,lm) word widx of pA[h]: W[2h+(q>>1)][widx&1]
            //   from src lane ((q&1)*2 + (widx>>1))*16 + lm
            union U8 { bf16x8 v; unsigned u[4]; };
            const int sA = ((lane >> 4) & 1) * 32 + lm;
            const int sB = sA + 16;
            const bool hi2 = (lane & 32) != 0;
            U8 pA[2][2];
#pragma unroll
            for (int qt = 0; qt < 2; ++qt)
#pragma unroll
                for (int hh = 0; hh < 2; ++hh) {
                    unsigned a0 = __shfl((int)Wd[qt][2 * hh][0], sA);
                    unsigned b0 = __shfl((int)Wd[qt][2 * hh + 1][0], sA);
                    pA[qt][hh].u[0] = hi2 ? b0 : a0;
                    unsigned a1 = __shfl((int)Wd[qt][2 * hh][1], sA);
                    unsigned b1 = __shfl((int)Wd[qt][2 * hh + 1][1], sA);
                    pA[qt][hh].u[1] = hi2 ? b1 : a1;
                    unsigned a2 = __shfl((int)Wd[qt][2 * hh][0], sB);
                    unsigned b2 = __shfl((int)Wd[qt][2 * hh + 1][0], sB);
                    pA[qt][hh].u[2] = hi2 ? b2 : a2;
                    unsigned a3 = __shfl((int)Wd[qt][2 * hh][1], sB);
                    unsigned b3 = __shfl((int)Wd[qt][2 * hh + 1][1], sB);
                    pA[qt][hh].u[3] = hi2 ? b3 : a3;
                }

            // aln for PV-layout rows (query q*4+r): replicated across q-groups, pull from group0
            float alno[2][4];
#pragma unroll
            for (int qt = 0; qt < 2; ++qt)
#pragma unroll
                for (int r = 0; r < 4; ++r)
                    alno[qt][r] = __shfl(alnv[qt], (lane >> 4) * 4 + r);

            // ---- PV: 32 MFMA (V frags preloaded from global)
#pragma unroll
            for (int nt = 0; nt < 8; ++nt) {
#pragma unroll
                for (int qt = 0; qt < 2; ++qt) {
                    f32x4 oo = o[qt][nt];
#pragma unroll
                    for (int r = 0; r < 4; ++r) oo[r] *= alno[qt][r];
                    oo = __builtin_amdgcn_mfma_f32_16x16x32_bf16(pA[qt][0].v, vf0[nt], oo, 0, 0, 0);
                    o[qt][nt] = __builtin_amdgcn_mfma_f32_16x16x32_bf16(pA[qt][1].v, vf1[nt], oo, 0, 0, 0);
                }
            }
        }

        // end-of-chunk: this wave's next-K loads landed; barrier makes all visible
        __builtin_amdgcn_sched_barrier(0);
        VMCNT(0);
        __builtin_amdgcn_s_barrier();
        __builtin_amdgcn_sched_barrier(0);
    }

    // epilogue: 1/l for PV-layout rows via shuffle from query-lane layout
    float invo[2][4];
#pragma unroll
    for (int qt = 0; qt < 2; ++qt) {
        float iv = 1.0f / lrow[qt];
#pragma unroll
        for (int r = 0; r < 4; ++r)
            invo[qt][r] = __shfl(iv, (lane >> 4) * 4 + r);
    }
#pragma unroll
    for (int qt = 0; qt < 2; ++qt)
#pragma unroll
        for (int nt = 0; nt < 8; ++nt) {
            int d = h * HDIM + lm + nt * 16;
#pragma unroll
            for (int r = 0; r < 4; ++r)
                ab[(size_t)(qw + qt * 16 + q * 4 + r) * DMODEL + d] =
                    f2bf(o[qt][nt][r] * invo[qt][r]);
        }
#undef ATT_STAGE
}

extern "C" void kernel_launch(void* const* d_in, const int* in_sizes, int n_in,
                              void* d_out, int out_size, void* d_ws, size_t ws_size,
                              hipStream_t stream) {
    const float* x  = (const float*)d_in[0];
    const float* wq = (const float*)d_in[1];
    const float* wk = (const float*)d_in[2];
    const float* wv = (const float*)d_in[3];
    const float* wo = (const float*)d_in[4];
    char* ws = (char*)d_ws;
    const size_t MB = 1024 * 1024;
    unsigned short* xb  = (unsigned short*)(ws + 0 * MB);
    unsigned short* qb  = (unsigned short*)(ws + 16 * MB);
    unsigned short* kb  = (unsigned short*)(ws + 32 * MB);
    unsigned short* vtb = (unsigned short*)(ws + 48 * MB);
    unsigned short* ab  = (unsigned short*)(ws + 64 * MB);
    unsigned short* wtb = (unsigned short*)(ws + 80 * MB);

    static int attr_done = 0;
    if (!attr_done) {
        hipFuncSetAttribute((const void*)&gemm8p_kernel<0>,
                            hipFuncAttributeMaxDynamicSharedMemorySize, 98304);
        hipFuncSetAttribute((const void*)&gemm8p_kernel<1>,
                            hipFuncAttributeMaxDynamicSharedMemorySize, 98304);
        hipFuncSetAttribute((const void*)&gemm8p_kernel<2>,
                            hipFuncAttributeMaxDynamicSharedMemorySize, 98304);
        attr_done = 1;
    }

    dim3 cg(64, 64);
    dim3 gg(32, 8);

    convert_x_kernel<<<(S_LEN * DMODEL / 4) / 256, 256, 0, stream>>>(x, xb, S_LEN * DMODEL / 4);

    convert_wt_kernel<<<cg, 256, 0, stream>>>(wq, wtb);
    gemm8p_kernel<0><<<gg, 512, 98304, stream>>>(xb, wtb, qb);
    convert_wt_kernel<<<cg, 256, 0, stream>>>(wk, wtb);
    gemm8p_kernel<0><<<gg, 512, 98304, stream>>>(xb, wtb, kb);
    convert_wt_kernel<<<cg, 256, 0, stream>>>(wv, wtb);
    gemm8p_kernel<1><<<gg, 512, 98304, stream>>>(xb, wtb, vtb);

    rope_kernel<<<(S_LEN * DMODEL / 2) / 256, 256, 0, stream>>>(qb, kb);

    attn_kernel<<<dim3(S_LEN / 128, NHEAD), 256, 0, stream>>>(qb, kb, vtb, ab);

    convert_wt_kernel<<<cg, 256, 0, stream>>>(wo, wtb);
    gemm8p_kernel<2><<<gg, 512, 98304, stream>>>(ab, wtb, d_out);
}

// Round 4
// 691.164 us; speedup vs baseline: 1.0765x; 1.0765x over previous
//
#include <hip/hip_runtime.h>
#include <stdint.h>

#define S_LEN 2048
#define DMODEL 4096
#define NHEAD 32
#define HDIM 128

typedef __attribute__((ext_vector_type(8))) short bf16x8;
typedef __attribute__((ext_vector_type(4))) float f32x4;

__device__ __forceinline__ unsigned short f2bf(float f) {
    union { float f; unsigned u; } v; v.f = f;
    unsigned u = v.u;
    unsigned r = (u + 0x7FFFu + ((u >> 16) & 1u)) >> 16;   // RNE
    return (unsigned short)r;
}
__device__ __forceinline__ float bf2f(unsigned short h) {
    union { unsigned u; float f; } v; v.u = ((unsigned)h) << 16;
    return v.f;
}

// ---------- elementwise f32 -> bf16 (4 per thread) ----------
__global__ void convert_x_kernel(const float* __restrict__ x,
                                 unsigned short* __restrict__ xb, int n4) {
    int t = blockIdx.x * blockDim.x + threadIdx.x;
    if (t >= n4) return;
    float4 v = ((const float4*)x)[t];
    ushort4 o;
    o.x = f2bf(v.x); o.y = f2bf(v.y); o.z = f2bf(v.z); o.w = f2bf(v.w);
    ((ushort4*)xb)[t] = o;
}

// ---------- transpose+convert weight: w[k][n] f32 -> wt[n][k] bf16 ----------
__global__ void convert_wt_kernel(const float* __restrict__ w,
                                  unsigned short* __restrict__ wt) {
    __shared__ unsigned short t[64][65];
    int n0 = blockIdx.x * 64, k0 = blockIdx.y * 64;
    for (int i = 0; i < 16; ++i) {
        int o = threadIdx.x + i * 256;
        int r = o >> 6, c = o & 63;
        t[r][c] = f2bf(w[(size_t)(k0 + r) * DMODEL + n0 + c]);
    }
    __syncthreads();
    for (int i = 0; i < 16; ++i) {
        int o = threadIdx.x + i * 256;
        int rr = o >> 6, kk = o & 63;
        wt[(size_t)(n0 + rr) * DMODEL + k0 + kk] = t[kk][rr];
    }
}

// ============================================================================
// GEMM: 8-phase counted-vmcnt schedule (verified; unchanged)
// ============================================================================

#define MFMA16(a, b, c) __builtin_amdgcn_mfma_f32_16x16x32_bf16(a, b, c, 0, 0, 0)

#define GLDS(g, l) __builtin_amdgcn_global_load_lds( \
    (__attribute__((address_space(1))) unsigned int*)(g), \
    (__attribute__((address_space(3))) unsigned int*)(l), 16, 0, 0)

#define VMCNT_(n) asm volatile("s_waitcnt vmcnt(" #n ")" ::: "memory")
#define VMCNT(n) VMCNT_(n)

#define PH_SYNC() \
    __builtin_amdgcn_sched_barrier(0); \
    __builtin_amdgcn_s_barrier(); \
    asm volatile("s_waitcnt lgkmcnt(0)" ::: "memory"); \
    __builtin_amdgcn_sched_barrier(0)

#define PH_END() \
    __builtin_amdgcn_s_setprio(0); \
    __builtin_amdgcn_sched_barrier(0); \
    __builtin_amdgcn_s_barrier(); \
    __builtin_amdgcn_sched_barrier(0)

#define PH_END_VM(VM) \
    __builtin_amdgcn_s_setprio(0); \
    __builtin_amdgcn_sched_barrier(0); \
    VMCNT(VM); \
    __builtin_amdgcn_s_barrier(); \
    __builtin_amdgcn_sched_barrier(0)

#define STAGE_A(T, PAR, J) do { \
    size_t ko_ = (size_t)(T) * 64 + (J) * 32; \
    GLDS(gA0 + ko_, As + ((PAR) * 2 + (J)) * 8192 + w * 512); \
    GLDS(gA1 + ko_, As + ((PAR) * 2 + (J)) * 8192 + 4096 + w * 512); \
} while (0)
#define STAGE_B(T, PAR, J) do { \
    size_t ko_ = (size_t)(T) * 64 + (J) * 32; \
    GLDS(gB + ko_, Bs + ((PAR) * 2 + (J)) * 4096 + w * 512); \
} while (0)

#define TILE(T, P, S1, S2, VM2, VM4) do { \
    const unsigned short* AsT = As + (P) * 16384; \
    const unsigned short* BsT = Bs + (P) * 8192; \
    bf16x8 af0, af1, af2, af3, bf0, bf1, bf2, bf3; \
    af0 = *(const bf16x8*)&AsT[offA0]; \
    af1 = *(const bf16x8*)&AsT[offA1]; \
    af2 = *(const bf16x8*)&AsT[offA2]; \
    af3 = *(const bf16x8*)&AsT[offA3]; \
    bf0 = *(const bf16x8*)&BsT[offB0]; \
    bf1 = *(const bf16x8*)&BsT[offB1]; \
    if (S1) STAGE_A((T) + 1, (P) ^ 1, 1); \
    PH_SYNC(); \
    __builtin_amdgcn_s_setprio(1); \
    acc[0][0] = MFMA16(af0, bf0, acc[0][0]); \
    acc[1][0] = MFMA16(af1, bf0, acc[1][0]); \
    acc[2][0] = MFMA16(af2, bf0, acc[2][0]); \
    acc[3][0] = MFMA16(af3, bf0, acc[3][0]); \
    acc[0][1] = MFMA16(af0, bf1, acc[0][1]); \
    acc[1][1] = MFMA16(af1, bf1, acc[1][1]); \
    acc[2][1] = MFMA16(af2, bf1, acc[2][1]); \
    acc[3][1] = MFMA16(af3, bf1, acc[3][1]); \
    PH_END(); \
    bf2 = *(const bf16x8*)&BsT[offB2]; \
    bf3 = *(const bf16x8*)&BsT[offB3]; \
    if (S1) STAGE_B((T) + 1, (P) ^ 1, 1); \
    PH_SYNC(); \
    __builtin_amdgcn_s_setprio(1); \
    acc[0][2] = MFMA16(af0, bf2, acc[0][2]); \
    acc[1][2] = MFMA16(af1, bf2, acc[1][2]); \
    acc[2][2] = MFMA16(af2, bf2, acc[2][2]); \
    acc[3][2] = MFMA16(af3, bf2, acc[3][2]); \
    acc[0][3] = MFMA16(af0, bf3, acc[0][3]); \
    acc[1][3] = MFMA16(af1, bf3, acc[1][3]); \
    acc[2][3] = MFMA16(af2, bf3, acc[2][3]); \
    acc[3][3] = MFMA16(af3, bf3, acc[3][3]); \
    PH_END_VM(VM2); \
    af0 = *(const bf16x8*)&AsT[8192 + offA0]; \
    af1 = *(const bf16x8*)&AsT[8192 + offA1]; \
    af2 = *(const bf16x8*)&AsT[8192 + offA2]; \
    af3 = *(const bf16x8*)&AsT[8192 + offA3]; \
    bf0 = *(const bf16x8*)&BsT[4096 + offB0]; \
    bf1 = *(const bf16x8*)&BsT[4096 + offB1]; \
    if (S2) STAGE_A((T) + 2, (P), 0); \
    PH_SYNC(); \
    __builtin_amdgcn_s_setprio(1); \
    acc[0][0] = MFMA16(af0, bf0, acc[0][0]); \
    acc[1][0] = MFMA16(af1, bf0, acc[1][0]); \
    acc[2][0] = MFMA16(af2, bf0, acc[2][0]); \
    acc[3][0] = MFMA16(af3, bf0, acc[3][0]); \
    acc[0][1] = MFMA16(af0, bf1, acc[0][1]); \
    acc[1][1] = MFMA16(af1, bf1, acc[1][1]); \
    acc[2][1] = MFMA16(af2, bf1, acc[2][1]); \
    acc[3][1] = MFMA16(af3, bf1, acc[3][1]); \
    PH_END(); \
    bf2 = *(const bf16x8*)&BsT[4096 + offB2]; \
    bf3 = *(const bf16x8*)&BsT[4096 + offB3]; \
    if (S2) STAGE_B((T) + 2, (P), 0); \
    PH_SYNC(); \
    __builtin_amdgcn_s_setprio(1); \
    acc[0][2] = MFMA16(af0, bf2, acc[0][2]); \
    acc[1][2] = MFMA16(af1, bf2, acc[1][2]); \
    acc[2][2] = MFMA16(af2, bf2, acc[2][2]); \
    acc[3][2] = MFMA16(af3, bf2, acc[3][2]); \
    acc[0][3] = MFMA16(af0, bf3, acc[0][3]); \
    acc[1][3] = MFMA16(af1, bf3, acc[1][3]); \
    acc[2][3] = MFMA16(af2, bf3, acc[2][3]); \
    acc[3][3] = MFMA16(af3, bf3, acc[3][3]); \
    PH_END_VM(VM4); \
} while (0)

template<int STORE_MODE>
__global__ __launch_bounds__(512, 2)
void gemm8p_kernel(const unsigned short* __restrict__ A,
                   const unsigned short* __restrict__ BT,
                   void* __restrict__ C) {
    constexpr int M = S_LEN, N = DMODEL, K = DMODEL;
    constexpr int NT = K / 64;
    extern __shared__ __align__(16) unsigned short sm[];
    unsigned short* As = sm;
    unsigned short* Bs = sm + 32768;

    const int tid = threadIdx.x;
    const int lane = tid & 63;
    const int w = tid >> 6;
    const int wr = w >> 1, wc = w & 1;
    const int q = lane >> 4, lm = lane & 15;

    int orig = blockIdx.y * gridDim.x + blockIdx.x;
    const int by = orig & 7;
    const int bx = orig >> 3;
    const int m0 = by * 256, n0 = bx * 128;

    const int c4 = tid & 3, r4 = tid >> 2, s4 = (tid >> 3) & 3;
    const unsigned short* gA0 = A + (size_t)(m0 + r4) * K + ((c4 ^ s4) * 8);
    const unsigned short* gA1 = gA0 + (size_t)128 * K;
    const unsigned short* gB  = BT + (size_t)(n0 + r4) * K + ((c4 ^ s4) * 8);

#define FRAGOFF(r_) ((r_) * 32 + ((q ^ (((r_) >> 1) & 3)) * 8))
    const int rA = wr * 64 + lm, rB = wc * 64 + lm;
    const int offA0 = FRAGOFF(rA);
    const int offA1 = FRAGOFF(rA + 16);
    const int offA2 = FRAGOFF(rA + 32);
    const int offA3 = FRAGOFF(rA + 48);
    const int offB0 = FRAGOFF(rB);
    const int offB1 = FRAGOFF(rB + 16);
    const int offB2 = FRAGOFF(rB + 32);
    const int offB3 = FRAGOFF(rB + 48);
#undef FRAGOFF

    f32x4 zero = {0.f, 0.f, 0.f, 0.f};
    f32x4 acc[4][4];
    for (int i = 0; i < 4; ++i)
        for (int j = 0; j < 4; ++j) acc[i][j] = zero;

    STAGE_A(0, 0, 0); STAGE_B(0, 0, 0);
    STAGE_A(0, 0, 1); STAGE_B(0, 0, 1);
    STAGE_A(1, 1, 0); STAGE_B(1, 1, 0);
    VMCNT(6);
    __builtin_amdgcn_s_barrier();
    __builtin_amdgcn_sched_barrier(0);

    for (int t = 0; t < NT - 2; t += 2) {
        TILE(t, 0, true, true, 6, 6);
        TILE(t + 1, 1, true, true, 6, 6);
    }
    TILE(NT - 2, 0, true, false, 6, 3);
    TILE(NT - 1, 1, false, false, 0, 0);

    for (int mi = 0; mi < 4; ++mi) {
        int mbase = m0 + wr * 64 + mi * 16 + q * 4;
        for (int ni = 0; ni < 4; ++ni) {
            int n = n0 + wc * 64 + ni * 16 + lm;
            if (STORE_MODE == 0) {
                unsigned short* Cb = (unsigned short*)C;
                for (int r = 0; r < 4; ++r)
                    Cb[(size_t)(mbase + r) * N + n] = f2bf(acc[mi][ni][r]);
            } else if (STORE_MODE == 1) {
                unsigned short* Cb = (unsigned short*)C;
                ushort4 v;
                v.x = f2bf(acc[mi][ni][0]); v.y = f2bf(acc[mi][ni][1]);
                v.z = f2bf(acc[mi][ni][2]); v.w = f2bf(acc[mi][ni][3]);
                *(ushort4*)&Cb[(size_t)n * M + mbase] = v;
            } else {
                float* Cf = (float*)C;
                for (int r = 0; r < 4; ++r)
                    Cf[(size_t)(mbase + r) * N + n] = acc[mi][ni][r];
            }
        }
    }
}

// ---------- RoPE in-place on q (fused 1/sqrt(hd)) and k ----------
__global__ void rope_kernel(unsigned short* __restrict__ qb,
                            unsigned short* __restrict__ kb) {
    int t = blockIdx.x * blockDim.x + threadIdx.x;
    if (t >= S_LEN * DMODEL / 2) return;
    int s = t >> 11;
    int p = t & 2047;
    int j = p & 63;
    float ang = (float)s * exp2f((float)j * -0.2076205059304602f);
    float sn, cs;
    sincosf(ang, &sn, &cs);
    size_t idx = (size_t)s * DMODEL + 2 * p;
    const float SC = 0.08838834764831845f;
    float a0 = bf2f(qb[idx]), a1 = bf2f(qb[idx + 1]);
    qb[idx]     = f2bf((a0 * cs - a1 * sn) * SC);
    qb[idx + 1] = f2bf((a0 * sn + a1 * cs) * SC);
    float b0 = bf2f(kb[idx]), b1 = bf2f(kb[idx + 1]);
    kb[idx]     = f2bf(b0 * cs - b1 * sn);
    kb[idx + 1] = f2bf(b0 * sn + b1 * cs);
}

// ============================================================================
// flash attention v5 = v3 body (known 163us) + XCD/CU load-balanced panel map.
// Triangular causal work: panel p (128 q) costs nch(p) = 2p+2 chunk-units.
// HW dispatch: linear block id b -> XCD (b&7); within XCD, round-robin over
// 32 CUs (slots s=b>>3; CU gets s and s+32). Map slots so each XCD gets
// panels {x, 15-x} for all 32 heads (per-XCD total = 32*34 = 1088 exactly),
// and CU-paired slots (s, s+32) carry the SAME head with panels (x, 15-x)
// -> exactly 34 chunk-units per CU under round-robin fill; no worse than the
// old map under other fill orders. Pure relabeling: correctness-independent.
// ============================================================================
__global__ __launch_bounds__(256, 2)
void attn_kernel(const unsigned short* __restrict__ qb,
                 const unsigned short* __restrict__ kb,
                 const unsigned short* __restrict__ vt,
                 unsigned short* __restrict__ ab) {
    __shared__ __align__(16) unsigned short Ks[64 * 128];   // [key][d], chunk c' = c ^ (key&15)
    __shared__ __align__(16) unsigned short VTs[128 * 64];  // [d][key], chunk c' = c ^ (d&7)
    __shared__ __align__(16) unsigned short Pb[4][32 * 72]; // per-wave P staging, pitch 72
    const int t = threadIdx.x;
    const int lane = t & 63;
    const int w = t >> 6;

    // balanced panel map (see header comment)
    const int b = blockIdx.x;           // 0..511, 1-D grid
    const int xcd = b & 7;
    const int slot = b >> 3;            // 0..63
    const int h = slot & 31;
    const int panel = (slot >> 5) == 0 ? xcd : 15 - xcd;
    const int q0 = panel * 128;

    const int qw = q0 + w * 32;                                    // wave's first query
    const int q = lane >> 4, lm = lane & 15;

    // staging assignment (fixed per thread, block-wide: 256 threads)
    const int krow = t >> 2;            // 0..63  (key row)
    const int kcol = t & 3;             // +i*4 -> 16 chunks/row
    const int vrow = t >> 1;            // 0..127 (d row)
    const int vcol = t & 1;             // +i*2 -> 8 chunks/row

    const unsigned short* gK = kb + (size_t)krow * DMODEL + h * HDIM;
    const unsigned short* gV = vt + (size_t)(h * HDIM + vrow) * S_LEN;

    // Q fragments for both 16-row q-tiles
    bf16x8 qf[2][4];
#pragma unroll
    for (int qt = 0; qt < 2; ++qt)
#pragma unroll
        for (int kc = 0; kc < 4; ++kc)
            qf[qt][kc] = *(const bf16x8*)&qb[(size_t)(qw + qt * 16 + lm) * DMODEL
                                            + h * HDIM + kc * 32 + q * 8];

    f32x4 zero = {0.f, 0.f, 0.f, 0.f};
    f32x4 o[2][8];
#pragma unroll
    for (int qt = 0; qt < 2; ++qt)
        for (int i = 0; i < 8; ++i) o[qt][i] = zero;
    float mrow[2][4], lrow[2][4];
#pragma unroll
    for (int qt = 0; qt < 2; ++qt)
        for (int r = 0; r < 4; ++r) { mrow[qt][r] = -1e30f; lrow[qt][r] = 0.f; }

    const int nch = q0 / 64 + 2;

    bf16x8 kreg[4], vreg[4];
    // prologue: stage chunk 0
#pragma unroll
    for (int i = 0; i < 4; ++i) {
        kreg[i] = *(const bf16x8*)&gK[(size_t)0 * DMODEL + (kcol + i * 4) * 8];
        vreg[i] = *(const bf16x8*)&gV[0 + (vcol + i * 2) * 8];
    }
#pragma unroll
    for (int i = 0; i < 4; ++i) {
        *(bf16x8*)&Ks[krow * 128 + (((kcol + i * 4) ^ (krow & 15)) * 8)] = kreg[i];
        *(bf16x8*)&VTs[vrow * 64 + (((vcol + i * 2) ^ (vrow & 7)) * 8)] = vreg[i];
    }
    __syncthreads();

    for (int c = 0; c < nch; ++c) {
        const int j0 = c * 64;
        // prefetch next chunk into registers (block-uniform)
        if (c + 1 < nch) {
            const size_t jn = (size_t)(j0 + 64);
#pragma unroll
            for (int i = 0; i < 4; ++i) {
                kreg[i] = *(const bf16x8*)&gK[jn * DMODEL + (kcol + i * 4) * 8];
                vreg[i] = *(const bf16x8*)&gV[jn + (vcol + i * 2) * 8];
            }
        }

        // wave-level causal skip: any unmasked (key<=query) pair in this chunk?
        if (j0 <= qw + 31) {
            // ---- QK^T: 16 K-frag reads shared by both q-tiles, 32 MFMA ----
            f32x4 s[2][4];
#pragma unroll
            for (int qt = 0; qt < 2; ++qt)
                for (int ks = 0; ks < 4; ++ks) s[qt][ks] = zero;
#pragma unroll
            for (int kc = 0; kc < 4; ++kc)
#pragma unroll
                for (int ks = 0; ks < 4; ++ks) {
                    bf16x8 kf = *(const bf16x8*)&Ks[(ks * 16 + lm) * 128
                                                    + (((kc * 4 + q) ^ lm) * 8)];
                    s[0][ks] = __builtin_amdgcn_mfma_f32_16x16x32_bf16(qf[0][kc], kf, s[0][ks], 0, 0, 0);
                    s[1][ks] = __builtin_amdgcn_mfma_f32_16x16x32_bf16(qf[1][kc], kf, s[1][ks], 0, 0, 0);
                }
            // causal mask (applies to every chunk overlapping the diagonal)
            if (j0 + 63 > qw) {
#pragma unroll
                for (int qt = 0; qt < 2; ++qt)
#pragma unroll
                    for (int ks = 0; ks < 4; ++ks)
#pragma unroll
                        for (int r = 0; r < 4; ++r)
                            if (j0 + ks * 16 + lm > qw + qt * 16 + q * 4 + r)
                                s[qt][ks][r] = -1e30f;
            }

            // ---- breadth-first online softmax over 8 rows ----
            float mx[2][4];
#pragma unroll
            for (int qt = 0; qt < 2; ++qt)
#pragma unroll
                for (int r = 0; r < 4; ++r)
                    mx[qt][r] = fmaxf(fmaxf(s[qt][0][r], s[qt][1][r]),
                                      fmaxf(s[qt][2][r], s[qt][3][r]));
#pragma unroll
            for (int st = 1; st <= 8; st <<= 1)
#pragma unroll
                for (int qt = 0; qt < 2; ++qt)
#pragma unroll
                    for (int r = 0; r < 4; ++r)
                        mx[qt][r] = fmaxf(mx[qt][r], __shfl_xor(mx[qt][r], st));

            float aln[2][4], mnv[2][4], rs[2][4];
#pragma unroll
            for (int qt = 0; qt < 2; ++qt)
#pragma unroll
                for (int r = 0; r < 4; ++r) {
                    mnv[qt][r] = fmaxf(mrow[qt][r], mx[qt][r]);
                    aln[qt][r] = __expf(mrow[qt][r] - mnv[qt][r]);
                    mrow[qt][r] = mnv[qt][r];
                }
#pragma unroll
            for (int qt = 0; qt < 2; ++qt)
#pragma unroll
                for (int ks = 0; ks < 4; ++ks)
#pragma unroll
                    for (int r = 0; r < 4; ++r)
                        s[qt][ks][r] = __expf(s[qt][ks][r] - mnv[qt][r]);
#pragma unroll
            for (int qt = 0; qt < 2; ++qt)
#pragma unroll
                for (int r = 0; r < 4; ++r)
                    rs[qt][r] = (s[qt][0][r] + s[qt][1][r]) + (s[qt][2][r] + s[qt][3][r]);
#pragma unroll
            for (int st = 1; st <= 8; st <<= 1)
#pragma unroll
                for (int qt = 0; qt < 2; ++qt)
#pragma unroll
                    for (int r = 0; r < 4; ++r)
                        rs[qt][r] += __shfl_xor(rs[qt][r], st);
#pragma unroll
            for (int qt = 0; qt < 2; ++qt)
#pragma unroll
                for (int r = 0; r < 4; ++r)
                    lrow[qt][r] = lrow[qt][r] * aln[qt][r] + rs[qt][r];

            // P -> per-wave LDS (transpose for PV A-operand)
#pragma unroll
            for (int qt = 0; qt < 2; ++qt)
#pragma unroll
                for (int ks = 0; ks < 4; ++ks)
#pragma unroll
                    for (int r = 0; r < 4; ++r)
                        Pb[w][(qt * 16 + q * 4 + r) * 72 + ks * 16 + lm] = f2bf(s[qt][ks][r]);

            bf16x8 pA[2][2];
#pragma unroll
            for (int qt = 0; qt < 2; ++qt) {
                pA[qt][0] = *(const bf16x8*)&Pb[w][(qt * 16 + lm) * 72 + q * 8];
                pA[qt][1] = *(const bf16x8*)&Pb[w][(qt * 16 + lm) * 72 + 32 + q * 8];
            }
            // ---- PV: 16 V-frag reads shared by both q-tiles, 32 MFMA ----
#pragma unroll
            for (int nt = 0; nt < 8; ++nt) {
                int d = nt * 16 + lm;
                bf16x8 vf0 = *(const bf16x8*)&VTs[d * 64 + ((q ^ (d & 7)) * 8)];
                bf16x8 vf1 = *(const bf16x8*)&VTs[d * 64 + (((4 + q) ^ (d & 7)) * 8)];
#pragma unroll
                for (int qt = 0; qt < 2; ++qt) {
                    f32x4 oo = o[qt][nt];
#pragma unroll
                    for (int r = 0; r < 4; ++r) oo[r] *= aln[qt][r];
                    oo = __builtin_amdgcn_mfma_f32_16x16x32_bf16(pA[qt][0], vf0, oo, 0, 0, 0);
                    o[qt][nt] = __builtin_amdgcn_mfma_f32_16x16x32_bf16(pA[qt][1], vf1, oo, 0, 0, 0);
                }
            }
        }

        __syncthreads();   // all waves done reading LDS chunk c
        if (c + 1 < nch) {
#pragma unroll
            for (int i = 0; i < 4; ++i) {
                *(bf16x8*)&Ks[krow * 128 + (((kcol + i * 4) ^ (krow & 15)) * 8)] = kreg[i];
                *(bf16x8*)&VTs[vrow * 64 + (((vcol + i * 2) ^ (vrow & 7)) * 8)] = vreg[i];
            }
        }
        __syncthreads();   // staging visible
    }

    float inv[2][4];
#pragma unroll
    for (int qt = 0; qt < 2; ++qt)
#pragma unroll
        for (int r = 0; r < 4; ++r) inv[qt][r] = 1.0f / lrow[qt][r];
#pragma unroll
    for (int qt = 0; qt < 2; ++qt)
#pragma unroll
        for (int nt = 0; nt < 8; ++nt) {
            int d = h * HDIM + lm + nt * 16;
#pragma unroll
            for (int r = 0; r < 4; ++r)
                ab[(size_t)(qw + qt * 16 + q * 4 + r) * DMODEL + d] =
                    f2bf(o[qt][nt][r] * inv[qt][r]);
        }
}

extern "C" void kernel_launch(void* const* d_in, const int* in_sizes, int n_in,
                              void* d_out, int out_size, void* d_ws, size_t ws_size,
                              hipStream_t stream) {
    const float* x  = (const float*)d_in[0];
    const float* wq = (const float*)d_in[1];
    const float* wk = (const float*)d_in[2];
    const float* wv = (const float*)d_in[3];
    const float* wo = (const float*)d_in[4];
    char* ws = (char*)d_ws;
    const size_t MB = 1024 * 1024;
    unsigned short* xb  = (unsigned short*)(ws + 0 * MB);
    unsigned short* qb  = (unsigned short*)(ws + 16 * MB);
    unsigned short* kb  = (unsigned short*)(ws + 32 * MB);
    unsigned short* vtb = (unsigned short*)(ws + 48 * MB);
    unsigned short* ab  = (unsigned short*)(ws + 64 * MB);
    unsigned short* wtb = (unsigned short*)(ws + 80 * MB);

    static int attr_done = 0;
    if (!attr_done) {
        hipFuncSetAttribute((const void*)&gemm8p_kernel<0>,
                            hipFuncAttributeMaxDynamicSharedMemorySize, 98304);
        hipFuncSetAttribute((const void*)&gemm8p_kernel<1>,
                            hipFuncAttributeMaxDynamicSharedMemorySize, 98304);
        hipFuncSetAttribute((const void*)&gemm8p_kernel<2>,
                            hipFuncAttributeMaxDynamicSharedMemorySize, 98304);
        attr_done = 1;
    }

    dim3 cg(64, 64);
    dim3 gg(32, 8);

    convert_x_kernel<<<(S_LEN * DMODEL / 4) / 256, 256, 0, stream>>>(x, xb, S_LEN * DMODEL / 4);

    convert_wt_kernel<<<cg, 256, 0, stream>>>(wq, wtb);
    gemm8p_kernel<0><<<gg, 512, 98304, stream>>>(xb, wtb, qb);
    convert_wt_kernel<<<cg, 256, 0, stream>>>(wk, wtb);
    gemm8p_kernel<0><<<gg, 512, 98304, stream>>>(xb, wtb, kb);
    convert_wt_kernel<<<cg, 256, 0, stream>>>(wv, wtb);
    gemm8p_kernel<1><<<gg, 512, 98304, stream>>>(xb, wtb, vtb);

    rope_kernel<<<(S_LEN * DMODEL / 2) / 256, 256, 0, stream>>>(qb, kb);

    attn_kernel<<<dim3(512), 256, 0, stream>>>(qb, kb, vtb, ab);

    convert_wt_kernel<<<cg, 256, 0, stream>>>(wo, wtb);
    gemm8p_kernel<2><<<gg, 512, 98304, stream>>>(ab, wtb, d_out);
}